// Round 14
// baseline (683.668 us; speedup 1.0000x reference)
//
#include <hip/hip_runtime.h>
#include <hip/hip_bf16.h>

#define BB 2
#define NN 4096
#define CC 512
#define HH 8
#define DD 64
#define KPIV 512
#define SCALE 0.125f
#define C2INV 4.8828125e-4f   /* 2^-11 */
#define C2    2048.0f         /* 2^11  */
#define NROWS 65536           /* BB*HH*NN */

typedef unsigned short ushort_t;
typedef __attribute__((ext_vector_type(8))) short short8;
typedef __attribute__((ext_vector_type(8))) _Float16 half8;
typedef __attribute__((ext_vector_type(16))) float float16;

__device__ __forceinline__ float bf2f(ushort_t h) {
    union { unsigned u; float f; } x; x.u = ((unsigned)h) << 16; return x.f;
}
__device__ __forceinline__ ushort_t f2bf(float f) {
    __hip_bfloat16 h = __float2bfloat16(f);
    ushort_t u;
    __builtin_memcpy(&u, &h, sizeof(u));
    return u;
}
// fp32 ~= hi + 2^-11 * lo, both f16, lo prescaled into normal range
__device__ __forceinline__ void split2h(float x, _Float16& hi, _Float16& lo) {
    hi = (_Float16)x;
    lo = (_Float16)((x - (float)hi) * C2);
}

// LDS column packing for the fp32 GEMM: col c -> 8-float groups at 12-float
// pitch. MUST be arithmetic +, not | (round 11 bug: OR aliased columns ->
// LDS write race -> corrupt q/k/v).
#define COLP(c) ((((c) >> 3) * 12) + ((c) & 7))
#define ROWSTR 196   /* floats per kk row */

// ---------------- K1: QKV projection GEMM, fp32 VALU (ranking-critical) -----
// NOTE: k and q feeding the importance ranking MUST be computed by this exact
// fp32 accumulation (round 9's MFMA-GEMM k flipped adjacent importance ranks).
// Round 12 single-buffer structure (dbuf regressed: LDS 2x -> occupancy drop,
// round 13) + REGISTER prefetch of the next tile (global latency hidden under
// compute, LDS stays 25 KB). Per-element FMA order unchanged -> outputs
// bitwise-identical.
// x,w fp32 -> q as (qh,ql) f16 PRESCALED by 0.125, k as (kh,kl) f16,
// v bf16 TRANSPOSED [B,H,D,N]
__global__ __launch_bounds__(256) void qkv_gemm_k(
    const float* __restrict__ x, const float* __restrict__ w,
    _Float16* __restrict__ qhg, _Float16* __restrict__ qlg,
    _Float16* __restrict__ khg, _Float16* __restrict__ klg,
    ushort_t* __restrict__ vt)
{
    __shared__ __attribute__((aligned(16))) float xs[16 * ROWSTR];
    __shared__ __attribute__((aligned(16))) float ws[16 * ROWSTR];
    const int t = threadIdx.x;
    const int row0 = blockIdx.x * 128;
    const int col0 = blockIdx.y * 128;
    const int tr = t & 15, tc = t >> 4;
    const int ts = col0 >> 9;   // tensor select, constant per block
    // fixed staging roles
    const int xr = t >> 1, xoff = (t & 1) * 8;      // x: row, k-offset
    const int wkk = t >> 4, wc8 = (t & 15) * 8;     // w: k-row, col group
    const float* xpb = x + (size_t)(row0 + xr) * CC + xoff;
    const float* wpb = w + (size_t)wkk * (3 * CC) + col0 + wc8;
    float acc[8][8] = {};
    float4 px0, px1, pw0, pw1;
    // prefetch tile 0
    px0 = *(const float4*)(xpb);
    px1 = *(const float4*)(xpb + 4);
    pw0 = *(const float4*)(wpb);
    pw1 = *(const float4*)(wpb + 4);
    for (int it = 0; it < 32; ++it) {
        __syncthreads();   // prev iter's LDS reads complete
        {   // write prefetched tile to LDS
            float xv[8] = {px0.x, px0.y, px0.z, px0.w, px1.x, px1.y, px1.z, px1.w};
            const int mc = COLP(xr);
            #pragma unroll
            for (int jj = 0; jj < 8; ++jj)
                xs[(xoff + jj) * ROWSTR + mc] = xv[jj];
            const int nc = wkk * ROWSTR + COLP(wc8);
            *(float4*)&ws[nc]     = pw0;
            *(float4*)&ws[nc + 4] = pw1;
        }
        __syncthreads();   // LDS ready
        if (it + 1 < 32) {  // prefetch next tile; latency hides under compute
            const int k0 = (it + 1) * 16;
            px0 = *(const float4*)(xpb + k0);
            px1 = *(const float4*)(xpb + k0 + 4);
            pw0 = *(const float4*)(wpb + (size_t)k0 * (3 * CC));
            pw1 = *(const float4*)(wpb + (size_t)k0 * (3 * CC) + 4);
        }
        #pragma unroll
        for (int kk = 0; kk < 16; ++kk) {
            float a[8], b[8];
            const int ab = kk * ROWSTR + tr * 12;   // COLP(tr*8) == tr*12
            const int bb = kk * ROWSTR + tc * 12;
            *(float4*)&a[0] = *(const float4*)&xs[ab];
            *(float4*)&a[4] = *(const float4*)&xs[ab + 4];
            *(float4*)&b[0] = *(const float4*)&ws[bb];
            *(float4*)&b[4] = *(const float4*)&ws[bb + 4];
            #pragma unroll
            for (int i = 0; i < 8; ++i)
                #pragma unroll
                for (int j = 0; j < 8; ++j)
                    acc[i][j] = fmaf(a[i], b[j], acc[i][j]);
        }
    }
    const int gc0 = col0 + tc * 8;
    const int hh = (gc0 >> 6) & 7;
    const int dd0 = gc0 & 63;                 // 8-col group within one head
    #pragma unroll
    for (int i = 0; i < 8; ++i) {
        const int grow = row0 + tr * 8 + i;
        const int b = grow >> 12, n = grow & (NN - 1);
        const size_t base = (((size_t)b * HH + hh) * NN + n) * DD + dd0;
        if (ts == 0) {
            half8 h8, l8;
            #pragma unroll
            for (int j = 0; j < 8; ++j) {
                _Float16 a2, b2; split2h(acc[i][j] * SCALE, a2, b2);  // exact *0.125
                h8[j] = a2; l8[j] = b2;
            }
            *(half8*)(qhg + base) = h8;
            *(half8*)(qlg + base) = l8;
        } else if (ts == 1) {
            half8 h8, l8;
            #pragma unroll
            for (int j = 0; j < 8; ++j) {
                _Float16 a2, b2; split2h(acc[i][j], a2, b2);
                h8[j] = a2; l8[j] = b2;
            }
            *(half8*)(khg + base) = h8;
            *(half8*)(klg + base) = l8;
        } else {
            // transposed v: [b,h,d,n] bf16 (scalar stores; one-time epilogue)
            #pragma unroll
            for (int j = 0; j < 8; ++j)
                vt[(((size_t)b * HH + hh) * DD + dd0 + j) * NN + n] = f2bf(acc[i][j]);
        }
    }
}

// ---------------- shared S machinery ----------------------------------------
// s = a0(qh.kh) + 2^-11 * a12(ql.kh + qh.kl)
// MFMA 32x32x16 layouts: A[m=lane&31][k=(lane>>5)*8+j], B[k][n=lane&31],
// C: col=lane&31, row=(reg&3)+8*(reg>>2)+4*(lane>>5)
__device__ __forceinline__ void load_q_frags(
    const _Float16* __restrict__ qhg, const _Float16* __restrict__ qlg,
    size_t qrow, int g, half8* qh, half8* ql)
{
    const size_t off = qrow * DD + g * 8;
    #pragma unroll
    for (int kd = 0; kd < 4; ++kd) {
        qh[kd] = *(const half8*)(qhg + off + kd * 16);
        ql[kd] = *(const half8*)(qlg + off + kd * 16);
    }
}

// stage 128 tokens (kh+kl) into LDS: pure copy
__device__ __forceinline__ void stage_k128(
    const _Float16* __restrict__ khg, const _Float16* __restrict__ klg,
    int bh, int n0, int t, half8* khs, half8* kls)
{
    const _Float16* kb = khg + ((size_t)bh * NN + n0) * DD;
    const _Float16* lb = klg + ((size_t)bh * NN + n0) * DD;
    #pragma unroll
    for (int j = 0; j < 4; ++j) {
        const int s = t + j * 256;
        const int seg = s >> 7, tok = s & 127;
        const size_t off = (size_t)tok * DD + seg * 8;
        *(uint4*)&khs[seg * 128 + tok] = *(const uint4*)(kb + off);
        *(uint4*)&kls[seg * 128 + tok] = *(const uint4*)(lb + off);
    }
}

#define S_STEP_LDS(khs, kls, t0)                                              \
    float16 a0, a12;                                                          \
    _Pragma("unroll")                                                         \
    for (int i = 0; i < 16; ++i) { a0[i] = 0.f; a12[i] = 0.f; }               \
    _Pragma("unroll")                                                         \
    for (int kd = 0; kd < 4; ++kd) {                                          \
        half8 bh8 = (khs)[(kd * 2 + g) * 128 + (t0) + ln];                    \
        half8 bl8 = (kls)[(kd * 2 + g) * 128 + (t0) + ln];                    \
        a0  = __builtin_amdgcn_mfma_f32_32x32x16_f16(qh[kd], bh8, a0, 0,0,0); \
        a12 = __builtin_amdgcn_mfma_f32_32x32x16_f16(ql[kd], bh8, a12,0,0,0); \
        a12 = __builtin_amdgcn_mfma_f32_32x32x16_f16(qh[kd], bl8, a12,0,0,0); \
    }

#define S_STEP_G(koff)                                                         \
    float16 a0, a12;                                                           \
    _Pragma("unroll")                                                          \
    for (int i = 0; i < 16; ++i) { a0[i] = 0.f; a12[i] = 0.f; }                \
    _Pragma("unroll")                                                          \
    for (int kd = 0; kd < 4; ++kd) {                                           \
        half8 bh8 = *(const half8*)(khg + (koff) + kd * 16);                   \
        half8 bl8 = *(const half8*)(klg + (koff) + kd * 16);                   \
        a0  = __builtin_amdgcn_mfma_f32_32x32x16_f16(qh[kd], bh8, a0, 0,0,0);  \
        a12 = __builtin_amdgcn_mfma_f32_32x32x16_f16(ql[kd], bh8, a12,0,0,0);  \
        a12 = __builtin_amdgcn_mfma_f32_32x32x16_f16(qh[kd], bl8, a12,0,0,0);  \
    }

// ---------------- K2: pass A — l partials, token-half split -----------------
// grid 1024 = (bh x qt) x 2 token-halves; 32 KB LDS -> 4 blocks/CU.
// lpart[th][row] = sum over that half's 2048 tokens; consumers use lp0+lp1
// (deterministic; importance shift ~3e-13 abs << rank gaps).
__global__ __launch_bounds__(256) void pass_a_k(
    const _Float16* __restrict__ qhg, const _Float16* __restrict__ qlg,
    const _Float16* __restrict__ khg, const _Float16* __restrict__ klg,
    float* __restrict__ lpart)
{
    __shared__ half8 khs[8 * 128];   // 16 KB
    __shared__ half8 kls[8 * 128];   // 16 KB
    const int t = threadIdx.x;
    const int lane = t & 63, wv = t >> 6;
    const int g = lane >> 5, ln = lane & 31;
    const int bh = blockIdx.x >> 6;
    const int qt = (blockIdx.x >> 1) & 31;
    const int th = blockIdx.x & 1;
    const int base_n = th * 2048;
    half8 qh[4], ql[4];
    load_q_frags(qhg, qlg, (size_t)bh * NN + qt * 128 + wv * 32 + ln, g, qh, ql);
    float rowacc[16];
    #pragma unroll
    for (int r = 0; r < 16; ++r) rowacc[r] = 0.f;
    for (int ss = 0; ss < 16; ++ss) {
        __syncthreads();
        stage_k128(khg, klg, bh, base_n + ss * 128, t, khs, kls);
        __syncthreads();
        #pragma unroll
        for (int ii = 0; ii < 4; ++ii) {
            S_STEP_LDS(khs, kls, ii * 32)
            #pragma unroll
            for (int r = 0; r < 16; ++r)
                rowacc[r] += __expf(fmaf(a12[r], C2INV, a0[r]));
        }
    }
    #pragma unroll
    for (int r = 0; r < 16; ++r) {
        float vs = rowacc[r];
        vs += __shfl_xor(vs, 1);
        vs += __shfl_xor(vs, 2);
        vs += __shfl_xor(vs, 4);
        vs += __shfl_xor(vs, 8);
        vs += __shfl_xor(vs, 16);
        rowacc[r] = vs;
    }
    if (ln == 0) {
        #pragma unroll
        for (int r = 0; r < 16; ++r) {
            const int row = (r & 3) + 8 * (r >> 2) + 4 * g;
            lpart[(size_t)th * NROWS + (size_t)bh * NN + qt * 128 + wv * 32 + row]
                = rowacc[r];
        }
    }
}

// ---------------- K3: pass B — column sums of P -> colsum[512][4096] --------
// grid 1024 = (bh x qt) x 2 token-halves; shared LDS staging (34 KB -> 4
// blocks/CU). Every colsum element written by exactly one block.
__global__ __launch_bounds__(256) void pass_b_k(
    const _Float16* __restrict__ qhg, const _Float16* __restrict__ qlg,
    const _Float16* __restrict__ khg, const _Float16* __restrict__ klg,
    const float* __restrict__ lpart, float* __restrict__ colsum)
{
    __shared__ half8 khs[8 * 128];    // 16 KB
    __shared__ half8 kls[8 * 128];    // 16 KB
    __shared__ float colbuf[4][128];  // 2 KB
    const int t = threadIdx.x;
    const int lane = t & 63, wv = t >> 6;
    const int g = lane >> 5, ln = lane & 31;
    const int bh = blockIdx.x >> 6;
    const int qt = (blockIdx.x >> 1) & 31;
    const int th = blockIdx.x & 1;
    const int rowout = blockIdx.x >> 1;       // bh*32 + qt
    const int base_n = th * 2048;
    half8 qh[4], ql[4];
    load_q_frags(qhg, qlg, (size_t)bh * NN + qt * 128 + wv * 32 + ln, g, qh, ql);
    float rv[16];
    #pragma unroll
    for (int r = 0; r < 16; ++r) {
        const int row = (r & 3) + 8 * (r >> 2) + 4 * g;
        const size_t li = (size_t)bh * NN + qt * 128 + wv * 32 + row;
        rv[r] = 1.0f / (lpart[li] + lpart[NROWS + li]);
    }
    for (int ss = 0; ss < 16; ++ss) {
        __syncthreads();   // prev compute reads + colbuf writes complete
        if (ss > 0 && t < 128)   // drain previous superstep's column sums
            colsum[(size_t)rowout * NN + base_n + (ss - 1) * 128 + t] =
                (colbuf[0][t] + colbuf[1][t]) + (colbuf[2][t] + colbuf[3][t]);
        stage_k128(khg, klg, bh, base_n + ss * 128, t, khs, kls);
        __syncthreads();   // staging visible; colbuf consumed
        #pragma unroll
        for (int ii = 0; ii < 4; ++ii) {
            S_STEP_LDS(khs, kls, ii * 32)
            float cs = 0.f;
            #pragma unroll
            for (int r = 0; r < 16; ++r)
                cs = fmaf(__expf(fmaf(a12[r], C2INV, a0[r])), rv[r], cs);
            cs += __shfl_xor(cs, 32);   // other 16-row half, same column
            if (g == 0) colbuf[wv][ii * 32 + ln] = cs;
        }
    }
    __syncthreads();
    if (t < 128)
        colsum[(size_t)rowout * NN + base_n + 2048 - 128 + t] =
            (colbuf[0][t] + colbuf[1][t]) + (colbuf[2][t] + colbuf[3][t]);
}

// ---------------- K4: reduce partials -> importance (fp64) ------------------
__global__ __launch_bounds__(256) void imp_reduce_k(
    const float* __restrict__ colsum, double* __restrict__ imp)
{
    const int n = blockIdx.x * 256 + threadIdx.x;   // 0..8191
    const int b = n >> 12, c = n & (NN - 1);
    const float* p = colsum + (size_t)b * 256 * NN + c;
    double s = 0.0;
    for (int i = 0; i < 256; ++i) s += (double)p[(size_t)i * NN];
    imp[n] = s * (1.0 / (double)(HH * NN));
}

// ---------------- K5: exact top-K via full bitonic sort on fp64 keys --------
__global__ __launch_bounds__(1024) void topk_k(
    const double* __restrict__ imp, int* __restrict__ idxout)
{
    __shared__ double sv[4096];
    __shared__ int si[4096];
    const int b = blockIdx.x, t = threadIdx.x;
    for (int i = t; i < 4096; i += 1024) { sv[i] = imp[b * 4096 + i]; si[i] = i; }
    __syncthreads();
    for (int kk = 2; kk <= 4096; kk <<= 1) {
        for (int j = kk >> 1; j > 0; j >>= 1) {
            #pragma unroll 1
            for (int r = 0; r < 2; ++r) {
                const int cm = t + r * 1024;
                const int i = ((cm & ~(j - 1)) << 1) | (cm & (j - 1));
                const int lo = i | j;
                const bool up = ((i & kk) == 0);
                const double va = sv[i], vb = sv[lo];
                const int ia = si[i], ib = si[lo];
                const bool after = (va < vb) || (va == vb && ia > ib);
                if (after == up) { sv[i] = vb; sv[lo] = va; si[i] = ib; si[lo] = ia; }
            }
            __syncthreads();
        }
    }
    if (t < KPIV) idxout[b * KPIV + t] = si[t];
}

// ---------------- K6: O = P@V for pivot rows, MFMA --------------------------
__global__ __launch_bounds__(256) void pass_c_k(
    const _Float16* __restrict__ qhg, const _Float16* __restrict__ qlg,
    const _Float16* __restrict__ khg, const _Float16* __restrict__ klg,
    const ushort_t* __restrict__ vt, const float* __restrict__ lpart,
    const int* __restrict__ idx, float* __restrict__ opiv)
{
    __shared__ short8 pfr[4][4][32];                            // [wv][kh*2+g][q]
    __shared__ __attribute__((aligned(16))) float osum[4][32][64];
    const int t = threadIdx.x;
    const int lane = t & 63, wv = t >> 6;
    const int g = lane >> 5, ln = lane & 31;
    const int bid = blockIdx.x;
    const int b = bid >> 8, h = (bid >> 5) & 7;
    const int chunk = (bid >> 1) & 15, th = bid & 1;
    const int bh = b * HH + h;
    const int r0 = chunk * 32;
    const int tokq = idx[b * KPIV + r0 + ln];
    half8 qh[4], ql[4];
    load_q_frags(qhg, qlg, (size_t)bh * NN + tokq, g, qh, ql);
    float rv[16];
    #pragma unroll
    for (int r = 0; r < 16; ++r) {
        const int row = (r & 3) + 8 * (r >> 2) + 4 * g;
        const size_t li = (size_t)bh * NN + idx[b * KPIV + r0 + row];
        rv[r] = 1.0f / (lpart[li] + lpart[NROWS + li]);
    }
    float16 oacc0, oacc1;
    #pragma unroll
    for (int i = 0; i < 16; ++i) { oacc0[i] = 0.f; oacc1[i] = 0.f; }
    const int base_n = th * 2048 + wv * 512;
    for (int step = 0; step < 16; ++step) {
        const int n0 = base_n + step * 32;
        const size_t koff = ((size_t)bh * NN + n0 + ln) * DD + g * 8;
        S_STEP_G(koff)
        __syncthreads();   // pfr(prev step) reads complete everywhere
        #pragma unroll
        for (int r = 0; r < 16; ++r) {
            const int row = (r & 3) + 8 * (r >> 2) + 4 * g;
            const float p = __expf(fmaf(a12[r], C2INV, a0[r])) * rv[r];
            *((ushort_t*)&pfr[wv][ln >> 3][row] + (ln & 7)) = f2bf(p);
        }
        __syncthreads();   // P visible
        #pragma unroll
        for (int kh2 = 0; kh2 < 2; ++kh2) {
            short8 pa = pfr[wv][kh2 * 2 + g][ln];
            const ushort_t* vp0 = vt + ((size_t)bh * DD + ln) * NN + n0 + kh2 * 16 + g * 8;
            uint4 u0 = *(const uint4*)vp0;
            uint4 u1 = *(const uint4*)(vp0 + (size_t)32 * NN);
            short8 vb0, vb1;
            __builtin_memcpy(&vb0, &u0, 16);
            __builtin_memcpy(&vb1, &u1, 16);
            oacc0 = __builtin_amdgcn_mfma_f32_32x32x16_bf16(pa, vb0, oacc0, 0,0,0);
            oacc1 = __builtin_amdgcn_mfma_f32_32x32x16_bf16(pa, vb1, oacc1, 0,0,0);
        }
    }
    #pragma unroll
    for (int r = 0; r < 16; ++r) {
        const int row = (r & 3) + 8 * (r >> 2) + 4 * g;
        osum[wv][row][ln]      = oacc0[r];
        osum[wv][row][32 + ln] = oacc1[r];
    }
    __syncthreads();
    {
        const int qrow = t >> 3, d0 = (t & 7) * 8;
        float s[8] = {};
        #pragma unroll
        for (int w = 0; w < 4; ++w) {
            float4 a  = *(const float4*)&osum[w][qrow][d0];
            float4 b2 = *(const float4*)&osum[w][qrow][d0 + 4];
            s[0] += a.x;  s[1] += a.y;  s[2] += a.z;  s[3] += a.w;
            s[4] += b2.x; s[5] += b2.y; s[6] += b2.z; s[7] += b2.w;
        }
        float* op = opiv + ((size_t)(b * KPIV + r0 + qrow)) * CC + h * DD + d0;
        #pragma unroll
        for (int j = 0; j < 8; ++j) atomicAdd(op + j, s[j]);
    }
}

// ---------------- K7: output projection of pivot rows -> fp32 out -----------
// grid 256 = 128 row-groups x 2 column-halves
__global__ __launch_bounds__(256) void proj_k(
    const float* __restrict__ opiv, const float* __restrict__ wp,
    const float* __restrict__ bp, float* __restrict__ out)
{
    __shared__ __attribute__((aligned(16))) float os[8][CC];
    const int t = threadIdx.x;
    const int r0 = (blockIdx.x >> 1) * 8;
    const int ch = blockIdx.x & 1;
    for (int f = t; f < 1024; f += 256) {
        const int rr = f >> 7, i = (f & 127) * 4;
        *(float4*)&os[rr][i] = *(const float4*)(opiv + (size_t)(r0 + rr) * CC + i);
    }
    __syncthreads();
    const int c0 = ch * 256 + t;
    float acc0[8] = {};
    for (int i = 0; i < CC; ++i) {
        const float w0 = wp[(size_t)i * CC + c0];
        #pragma unroll
        for (int rr = 0; rr < 8; ++rr)
            acc0[rr] = fmaf(os[rr][i], w0, acc0[rr]);
    }
    const float b0 = bp[c0];
    #pragma unroll
    for (int rr = 0; rr < 8; ++rr)
        out[((size_t)(r0 + rr)) * CC + c0] = acc0[rr] + b0;
}

extern "C" void kernel_launch(void* const* d_in, const int* in_sizes, int n_in,
                              void* d_out, int out_size, void* d_ws, size_t ws_size,
                              hipStream_t stream)
{
    const float* x     = (const float*)d_in[0];
    const float* wqkv  = (const float*)d_in[1];
    const float* wproj = (const float*)d_in[2];
    const float* bproj = (const float*)d_in[3];

    // workspace layout: ~50.6 MiB total (all q/k as f16 pairs)
    const size_t NE = (size_t)BB * HH * NN * DD;   // 4.19M elements
    _Float16*  qhg    = (_Float16*)d_ws;                               // 8.39 MB
    _Float16*  qlg    = qhg + NE;                                      // 8.39 MB
    _Float16*  khg    = qlg + NE;                                      // 8.39 MB
    _Float16*  klg    = khg + NE;                                      // 8.39 MB
    ushort_t*  v      = (ushort_t*)(klg + NE);                         // 8.39 MB (d-major)
    float*     lpart  = (float*)(v + NE);                              // 0.52 MB (2 halves)
    float*     colsum = lpart + (size_t)2 * NROWS;                     // 8.39 MB
    double*    imp    = (double*)(colsum + (size_t)512 * NN);          // 0.07 MB
    int*       idx    = (int*)(imp + BB * NN);                         // 4 KB
    float*     opiv   = (float*)(idx + BB * KPIV);                     // 2.10 MB
    float*     out    = (float*)d_out;

    const size_t need = (size_t)((char*)(opiv + (size_t)BB * KPIV * CC) - (char*)d_ws);
    if (ws_size < need) return;   // signature: out stays 0 -> absmax ~0.254

    qkv_gemm_k<<<dim3(64, 12), 256, 0, stream>>>(x, wqkv, qhg, qlg, khg, klg, v);
    pass_a_k<<<1024, 256, 0, stream>>>(qhg, qlg, khg, klg, lpart);
    pass_b_k<<<1024, 256, 0, stream>>>(qhg, qlg, khg, klg, lpart, colsum);
    imp_reduce_k<<<32, 256, 0, stream>>>(colsum, imp);
    topk_k<<<2, 1024, 0, stream>>>(imp, idx);
    hipMemsetAsync(opiv, 0, (size_t)BB * KPIV * CC * sizeof(float), stream);
    pass_c_k<<<512, 256, 0, stream>>>(qhg, qlg, khg, klg, v, lpart, idx, opiv);
    proj_k<<<256, 256, 0, stream>>>(opiv, wproj, bproj, out);
}

// Round 15
// 658.876 us; speedup vs baseline: 1.0376x; 1.0376x over previous
//
#include <hip/hip_runtime.h>
#include <hip/hip_bf16.h>

#define BB 2
#define NN 4096
#define CC 512
#define HH 8
#define DD 64
#define KPIV 512
#define SCALE 0.125f
#define C2INV 4.8828125e-4f   /* 2^-11 */
#define C2    2048.0f         /* 2^11  */
#define NROWS 65536           /* BB*HH*NN */

typedef unsigned short ushort_t;
typedef __attribute__((ext_vector_type(8))) short short8;
typedef __attribute__((ext_vector_type(8))) _Float16 half8;
typedef __attribute__((ext_vector_type(16))) float float16;

__device__ __forceinline__ float bf2f(ushort_t h) {
    union { unsigned u; float f; } x; x.u = ((unsigned)h) << 16; return x.f;
}
__device__ __forceinline__ ushort_t f2bf(float f) {
    __hip_bfloat16 h = __float2bfloat16(f);
    ushort_t u;
    __builtin_memcpy(&u, &h, sizeof(u));
    return u;
}
// fp32 ~= hi + 2^-11 * lo, both f16, lo prescaled into normal range
__device__ __forceinline__ void split2h(float x, _Float16& hi, _Float16& lo) {
    hi = (_Float16)x;
    lo = (_Float16)((x - (float)hi) * C2);
}

// LDS column packing for the fp32 GEMM: col c -> 8-float groups at 12-float
// pitch. MUST be arithmetic +, not | (round 11 bug: OR aliased columns ->
// LDS write race -> corrupt q/k/v).
#define COLP(c) ((((c) >> 3) * 12) + ((c) & 7))
#define ROWSTR 196   /* floats per kk row */

// ---------------- K1a: Q/K projection GEMM, fp32 VALU (ranking-critical) ----
// NOTE: k and q feeding the importance ranking MUST be computed by this exact
// fp32 accumulation (round 9's MFMA-GEMM k flipped adjacent importance ranks).
// Round 14 kernel verbatim, restricted to cols 0..1023 (q,k) — v moved to the
// MFMA kernel below (value-path only). q/k outputs bitwise-identical.
// x,w fp32 -> q as (qh,ql) f16 PRESCALED by 0.125, k as (kh,kl) f16
__global__ __launch_bounds__(256) void qkv_gemm_k(
    const float* __restrict__ x, const float* __restrict__ w,
    _Float16* __restrict__ qhg, _Float16* __restrict__ qlg,
    _Float16* __restrict__ khg, _Float16* __restrict__ klg)
{
    __shared__ __attribute__((aligned(16))) float xs[16 * ROWSTR];
    __shared__ __attribute__((aligned(16))) float ws[16 * ROWSTR];
    const int t = threadIdx.x;
    const int row0 = blockIdx.x * 128;
    const int col0 = blockIdx.y * 128;        // 0..1023: ts in {0,1}
    const int tr = t & 15, tc = t >> 4;
    const int ts = col0 >> 9;   // 0=q 1=k, constant per block
    // fixed staging roles
    const int xr = t >> 1, xoff = (t & 1) * 8;      // x: row, k-offset
    const int wkk = t >> 4, wc8 = (t & 15) * 8;     // w: k-row, col group
    const float* xpb = x + (size_t)(row0 + xr) * CC + xoff;
    const float* wpb = w + (size_t)wkk * (3 * CC) + col0 + wc8;
    float acc[8][8] = {};
    float4 px0, px1, pw0, pw1;
    px0 = *(const float4*)(xpb);
    px1 = *(const float4*)(xpb + 4);
    pw0 = *(const float4*)(wpb);
    pw1 = *(const float4*)(wpb + 4);
    for (int it = 0; it < 32; ++it) {
        __syncthreads();   // prev iter's LDS reads complete
        {   // write prefetched tile to LDS
            float xv[8] = {px0.x, px0.y, px0.z, px0.w, px1.x, px1.y, px1.z, px1.w};
            const int mc = COLP(xr);
            #pragma unroll
            for (int jj = 0; jj < 8; ++jj)
                xs[(xoff + jj) * ROWSTR + mc] = xv[jj];
            const int nc = wkk * ROWSTR + COLP(wc8);
            *(float4*)&ws[nc]     = pw0;
            *(float4*)&ws[nc + 4] = pw1;
        }
        __syncthreads();   // LDS ready
        if (it + 1 < 32) {  // prefetch next tile; latency hides under compute
            const int k0 = (it + 1) * 16;
            px0 = *(const float4*)(xpb + k0);
            px1 = *(const float4*)(xpb + k0 + 4);
            pw0 = *(const float4*)(wpb + (size_t)k0 * (3 * CC));
            pw1 = *(const float4*)(wpb + (size_t)k0 * (3 * CC) + 4);
        }
        #pragma unroll
        for (int kk = 0; kk < 16; ++kk) {
            float a[8], b[8];
            const int ab = kk * ROWSTR + tr * 12;   // COLP(tr*8) == tr*12
            const int bb = kk * ROWSTR + tc * 12;
            *(float4*)&a[0] = *(const float4*)&xs[ab];
            *(float4*)&a[4] = *(const float4*)&xs[ab + 4];
            *(float4*)&b[0] = *(const float4*)&ws[bb];
            *(float4*)&b[4] = *(const float4*)&ws[bb + 4];
            #pragma unroll
            for (int i = 0; i < 8; ++i)
                #pragma unroll
                for (int j = 0; j < 8; ++j)
                    acc[i][j] = fmaf(a[i], b[j], acc[i][j]);
        }
    }
    const int gc0 = col0 + tc * 8;
    const int hh = (gc0 >> 6) & 7;
    const int dd0 = gc0 & 63;                 // 8-col group within one head
    #pragma unroll
    for (int i = 0; i < 8; ++i) {
        const int grow = row0 + tr * 8 + i;
        const int b = grow >> 12, n = grow & (NN - 1);
        const size_t base = (((size_t)b * HH + hh) * NN + n) * DD + dd0;
        if (ts == 0) {
            half8 h8, l8;
            #pragma unroll
            for (int j = 0; j < 8; ++j) {
                _Float16 a2, b2; split2h(acc[i][j] * SCALE, a2, b2);  // exact *0.125
                h8[j] = a2; l8[j] = b2;
            }
            *(half8*)(qhg + base) = h8;
            *(half8*)(qlg + base) = l8;
        } else {
            half8 h8, l8;
            #pragma unroll
            for (int j = 0; j < 8; ++j) {
                _Float16 a2, b2; split2h(acc[i][j], a2, b2);
                h8[j] = a2; l8[j] = b2;
            }
            *(half8*)(khg + base) = h8;
            *(half8*)(klg + base) = l8;
        }
    }
}

// ---------------- K1b: V projection GEMM via split-f16 MFMA (value path) ----
// v = x @ w[:,1024:1536], output bf16 TRANSPOSED [B,H,D,N]. Value-path only
// (threshold 5.1e-3; split error ~1e-6) — NOT used for ranking.
// Block 128 rows x 64 cols, 4 waves, wave owns 32 rows x 2 col-tiles.
// MFMA 32x32x16 layouts: A[m=lane&31][k=(lane>>5)*8+j], B[k][n=lane&31],
// C: col=lane&31, row=(reg&3)+8*(reg>>2)+4*(lane>>5)
__global__ __launch_bounds__(256) void v_gemm_k(
    const float* __restrict__ x, const float* __restrict__ w,
    ushort_t* __restrict__ vt)
{
    __shared__ __attribute__((aligned(16))) _Float16 xh[128 * 24];
    __shared__ __attribute__((aligned(16))) _Float16 xl[128 * 24];
    __shared__ __attribute__((aligned(16))) _Float16 wh[64 * 24];
    __shared__ __attribute__((aligned(16))) _Float16 wl[64 * 24];
    const int t = threadIdx.x;
    const int lane = t & 63, wv = t >> 6;
    const int g = lane >> 5, ln = lane & 31;
    const int row0 = blockIdx.x * 128;
    const int col0 = 1024 + blockIdx.y * 64;
    const int hh = (col0 >> 6) & 7;
    const int b = row0 >> 12;
    float16 a0[2], a12[2];
    #pragma unroll
    for (int c = 0; c < 2; ++c)
        #pragma unroll
        for (int i = 0; i < 16; ++i) { a0[c][i] = 0.f; a12[c][i] = 0.f; }
    for (int k0 = 0; k0 < CC; k0 += 16) {
        __syncthreads();
        {   // stage x tile 128 rows x 16 k, split -> f16 pair, A-frag layout
            const int r = t >> 1, kk0 = (t & 1) * 8;
            const float* xp = x + (size_t)(row0 + r) * CC + k0 + kk0;
            float4 f0 = *(const float4*)xp;
            float4 f1 = *(const float4*)(xp + 4);
            float xv[8] = {f0.x, f0.y, f0.z, f0.w, f1.x, f1.y, f1.z, f1.w};
            half8 h8, l8;
            #pragma unroll
            for (int j = 0; j < 8; ++j) {
                _Float16 a2, b2; split2h(xv[j], a2, b2);
                h8[j] = a2; l8[j] = b2;
            }
            *(half8*)&xh[r * 24 + kk0] = h8;
            *(half8*)&xl[r * 24 + kk0] = l8;
        }
        {   // stage w tile 16 k x 64 cols, split, B-frag layout (col-major)
            const int kk = t & 15, c4 = (t >> 4) * 4;
            float4 f = *(const float4*)(w + (size_t)(k0 + kk) * (3 * CC) + col0 + c4);
            float wv4[4] = {f.x, f.y, f.z, f.w};
            #pragma unroll
            for (int j = 0; j < 4; ++j) {
                _Float16 a2, b2; split2h(wv4[j], a2, b2);
                wh[(c4 + j) * 24 + kk] = a2;
                wl[(c4 + j) * 24 + kk] = b2;
            }
        }
        __syncthreads();
        half8 ah = *(half8*)&xh[(wv * 32 + ln) * 24 + g * 8];
        half8 al = *(half8*)&xl[(wv * 32 + ln) * 24 + g * 8];
        #pragma unroll
        for (int c = 0; c < 2; ++c) {
            half8 bh8 = *(half8*)&wh[(c * 32 + ln) * 24 + g * 8];
            half8 bl8 = *(half8*)&wl[(c * 32 + ln) * 24 + g * 8];
            a0[c]  = __builtin_amdgcn_mfma_f32_32x32x16_f16(ah, bh8, a0[c], 0,0,0);
            a12[c] = __builtin_amdgcn_mfma_f32_32x32x16_f16(al, bh8, a12[c],0,0,0);
            a12[c] = __builtin_amdgcn_mfma_f32_32x32x16_f16(ah, bl8, a12[c],0,0,0);
        }
    }
    // epilogue: transposed v [b,h,d,n]; reg quad rq covers 4 consecutive n
    #pragma unroll
    for (int c = 0; c < 2; ++c) {
        const int d = c * 32 + ln;
        #pragma unroll
        for (int rq = 0; rq < 4; ++rq) {
            const int nbase = row0 + wv * 32 + 8 * rq + 4 * g;
            ushort_t pk[4];
            #pragma unroll
            for (int i = 0; i < 4; ++i) {
                const int r = rq * 4 + i;
                pk[i] = f2bf(fmaf(a12[c][r], C2INV, a0[c][r]));
            }
            __builtin_memcpy(
                vt + ((size_t)(b * HH + hh) * DD + d) * NN + (nbase & (NN - 1)),
                pk, 8);
        }
    }
}

// ---------------- shared S machinery ----------------------------------------
// s = a0(qh.kh) + 2^-11 * a12(ql.kh + qh.kl)
__device__ __forceinline__ void load_q_frags(
    const _Float16* __restrict__ qhg, const _Float16* __restrict__ qlg,
    size_t qrow, int g, half8* qh, half8* ql)
{
    const size_t off = qrow * DD + g * 8;
    #pragma unroll
    for (int kd = 0; kd < 4; ++kd) {
        qh[kd] = *(const half8*)(qhg + off + kd * 16);
        ql[kd] = *(const half8*)(qlg + off + kd * 16);
    }
}

// stage 128 tokens (kh+kl) into LDS: pure copy
__device__ __forceinline__ void stage_k128(
    const _Float16* __restrict__ khg, const _Float16* __restrict__ klg,
    int bh, int n0, int t, half8* khs, half8* kls)
{
    const _Float16* kb = khg + ((size_t)bh * NN + n0) * DD;
    const _Float16* lb = klg + ((size_t)bh * NN + n0) * DD;
    #pragma unroll
    for (int j = 0; j < 4; ++j) {
        const int s = t + j * 256;
        const int seg = s >> 7, tok = s & 127;
        const size_t off = (size_t)tok * DD + seg * 8;
        *(uint4*)&khs[seg * 128 + tok] = *(const uint4*)(kb + off);
        *(uint4*)&kls[seg * 128 + tok] = *(const uint4*)(lb + off);
    }
}

#define S_STEP_LDS(khs, kls, t0)                                              \
    float16 a0, a12;                                                          \
    _Pragma("unroll")                                                         \
    for (int i = 0; i < 16; ++i) { a0[i] = 0.f; a12[i] = 0.f; }               \
    _Pragma("unroll")                                                         \
    for (int kd = 0; kd < 4; ++kd) {                                          \
        half8 bh8 = (khs)[(kd * 2 + g) * 128 + (t0) + ln];                    \
        half8 bl8 = (kls)[(kd * 2 + g) * 128 + (t0) + ln];                    \
        a0  = __builtin_amdgcn_mfma_f32_32x32x16_f16(qh[kd], bh8, a0, 0,0,0); \
        a12 = __builtin_amdgcn_mfma_f32_32x32x16_f16(ql[kd], bh8, a12,0,0,0); \
        a12 = __builtin_amdgcn_mfma_f32_32x32x16_f16(qh[kd], bl8, a12,0,0,0); \
    }

#define S_STEP_G(koff)                                                         \
    float16 a0, a12;                                                           \
    _Pragma("unroll")                                                          \
    for (int i = 0; i < 16; ++i) { a0[i] = 0.f; a12[i] = 0.f; }                \
    _Pragma("unroll")                                                          \
    for (int kd = 0; kd < 4; ++kd) {                                           \
        half8 bh8 = *(const half8*)(khg + (koff) + kd * 16);                   \
        half8 bl8 = *(const half8*)(klg + (koff) + kd * 16);                   \
        a0  = __builtin_amdgcn_mfma_f32_32x32x16_f16(qh[kd], bh8, a0, 0,0,0);  \
        a12 = __builtin_amdgcn_mfma_f32_32x32x16_f16(ql[kd], bh8, a12,0,0,0);  \
        a12 = __builtin_amdgcn_mfma_f32_32x32x16_f16(qh[kd], bl8, a12,0,0,0);  \
    }

// ---------------- K2: pass A — l partials, token-half split -----------------
__global__ __launch_bounds__(256) void pass_a_k(
    const _Float16* __restrict__ qhg, const _Float16* __restrict__ qlg,
    const _Float16* __restrict__ khg, const _Float16* __restrict__ klg,
    float* __restrict__ lpart)
{
    __shared__ half8 khs[8 * 128];   // 16 KB
    __shared__ half8 kls[8 * 128];   // 16 KB
    const int t = threadIdx.x;
    const int lane = t & 63, wv = t >> 6;
    const int g = lane >> 5, ln = lane & 31;
    const int bh = blockIdx.x >> 6;
    const int qt = (blockIdx.x >> 1) & 31;
    const int th = blockIdx.x & 1;
    const int base_n = th * 2048;
    half8 qh[4], ql[4];
    load_q_frags(qhg, qlg, (size_t)bh * NN + qt * 128 + wv * 32 + ln, g, qh, ql);
    float rowacc[16];
    #pragma unroll
    for (int r = 0; r < 16; ++r) rowacc[r] = 0.f;
    for (int ss = 0; ss < 16; ++ss) {
        __syncthreads();
        stage_k128(khg, klg, bh, base_n + ss * 128, t, khs, kls);
        __syncthreads();
        #pragma unroll
        for (int ii = 0; ii < 4; ++ii) {
            S_STEP_LDS(khs, kls, ii * 32)
            #pragma unroll
            for (int r = 0; r < 16; ++r)
                rowacc[r] += __expf(fmaf(a12[r], C2INV, a0[r]));
        }
    }
    #pragma unroll
    for (int r = 0; r < 16; ++r) {
        float vs = rowacc[r];
        vs += __shfl_xor(vs, 1);
        vs += __shfl_xor(vs, 2);
        vs += __shfl_xor(vs, 4);
        vs += __shfl_xor(vs, 8);
        vs += __shfl_xor(vs, 16);
        rowacc[r] = vs;
    }
    if (ln == 0) {
        #pragma unroll
        for (int r = 0; r < 16; ++r) {
            const int row = (r & 3) + 8 * (r >> 2) + 4 * g;
            lpart[(size_t)th * NROWS + (size_t)bh * NN + qt * 128 + wv * 32 + row]
                = rowacc[r];
        }
    }
}

// ---------------- K3: pass B — column sums of P -> colsum[512][4096] --------
__global__ __launch_bounds__(256) void pass_b_k(
    const _Float16* __restrict__ qhg, const _Float16* __restrict__ qlg,
    const _Float16* __restrict__ khg, const _Float16* __restrict__ klg,
    const float* __restrict__ lpart, float* __restrict__ colsum)
{
    __shared__ half8 khs[8 * 128];    // 16 KB
    __shared__ half8 kls[8 * 128];    // 16 KB
    __shared__ float colbuf[4][128];  // 2 KB
    const int t = threadIdx.x;
    const int lane = t & 63, wv = t >> 6;
    const int g = lane >> 5, ln = lane & 31;
    const int bh = blockIdx.x >> 6;
    const int qt = (blockIdx.x >> 1) & 31;
    const int th = blockIdx.x & 1;
    const int rowout = blockIdx.x >> 1;       // bh*32 + qt
    const int base_n = th * 2048;
    half8 qh[4], ql[4];
    load_q_frags(qhg, qlg, (size_t)bh * NN + qt * 128 + wv * 32 + ln, g, qh, ql);
    float rv[16];
    #pragma unroll
    for (int r = 0; r < 16; ++r) {
        const int row = (r & 3) + 8 * (r >> 2) + 4 * g;
        const size_t li = (size_t)bh * NN + qt * 128 + wv * 32 + row;
        rv[r] = 1.0f / (lpart[li] + lpart[NROWS + li]);
    }
    for (int ss = 0; ss < 16; ++ss) {
        __syncthreads();   // prev compute reads + colbuf writes complete
        if (ss > 0 && t < 128)   // drain previous superstep's column sums
            colsum[(size_t)rowout * NN + base_n + (ss - 1) * 128 + t] =
                (colbuf[0][t] + colbuf[1][t]) + (colbuf[2][t] + colbuf[3][t]);
        stage_k128(khg, klg, bh, base_n + ss * 128, t, khs, kls);
        __syncthreads();   // staging visible; colbuf consumed
        #pragma unroll
        for (int ii = 0; ii < 4; ++ii) {
            S_STEP_LDS(khs, kls, ii * 32)
            float cs = 0.f;
            #pragma unroll
            for (int r = 0; r < 16; ++r)
                cs = fmaf(__expf(fmaf(a12[r], C2INV, a0[r])), rv[r], cs);
            cs += __shfl_xor(cs, 32);   // other 16-row half, same column
            if (g == 0) colbuf[wv][ii * 32 + ln] = cs;
        }
    }
    __syncthreads();
    if (t < 128)
        colsum[(size_t)rowout * NN + base_n + 2048 - 128 + t] =
            (colbuf[0][t] + colbuf[1][t]) + (colbuf[2][t] + colbuf[3][t]);
}

// ---------------- K4: reduce partials -> importance (fp64) ------------------
__global__ __launch_bounds__(256) void imp_reduce_k(
    const float* __restrict__ colsum, double* __restrict__ imp)
{
    const int n = blockIdx.x * 256 + threadIdx.x;   // 0..8191
    const int b = n >> 12, c = n & (NN - 1);
    const float* p = colsum + (size_t)b * 256 * NN + c;
    double s = 0.0;
    for (int i = 0; i < 256; ++i) s += (double)p[(size_t)i * NN];
    imp[n] = s * (1.0 / (double)(HH * NN));
}

// ---------------- K5: exact top-K via full bitonic sort on fp64 keys --------
__global__ __launch_bounds__(1024) void topk_k(
    const double* __restrict__ imp, int* __restrict__ idxout)
{
    __shared__ double sv[4096];
    __shared__ int si[4096];
    const int b = blockIdx.x, t = threadIdx.x;
    for (int i = t; i < 4096; i += 1024) { sv[i] = imp[b * 4096 + i]; si[i] = i; }
    __syncthreads();
    for (int kk = 2; kk <= 4096; kk <<= 1) {
        for (int j = kk >> 1; j > 0; j >>= 1) {
            #pragma unroll 1
            for (int r = 0; r < 2; ++r) {
                const int cm = t + r * 1024;
                const int i = ((cm & ~(j - 1)) << 1) | (cm & (j - 1));
                const int lo = i | j;
                const bool up = ((i & kk) == 0);
                const double va = sv[i], vb = sv[lo];
                const int ia = si[i], ib = si[lo];
                const bool after = (va < vb) || (va == vb && ia > ib);
                if (after == up) { sv[i] = vb; sv[lo] = va; si[i] = ib; si[lo] = ia; }
            }
            __syncthreads();
        }
    }
    if (t < KPIV) idxout[b * KPIV + t] = si[t];
}

// ---------------- K6: O = P@V for pivot rows, MFMA --------------------------
__global__ __launch_bounds__(256) void pass_c_k(
    const _Float16* __restrict__ qhg, const _Float16* __restrict__ qlg,
    const _Float16* __restrict__ khg, const _Float16* __restrict__ klg,
    const ushort_t* __restrict__ vt, const float* __restrict__ lpart,
    const int* __restrict__ idx, float* __restrict__ opiv)
{
    __shared__ short8 pfr[4][4][32];                            // [wv][kh*2+g][q]
    __shared__ __attribute__((aligned(16))) float osum[4][32][64];
    const int t = threadIdx.x;
    const int lane = t & 63, wv = t >> 6;
    const int g = lane >> 5, ln = lane & 31;
    const int bid = blockIdx.x;
    const int b = bid >> 8, h = (bid >> 5) & 7;
    const int chunk = (bid >> 1) & 15, th = bid & 1;
    const int bh = b * HH + h;
    const int r0 = chunk * 32;
    const int tokq = idx[b * KPIV + r0 + ln];
    half8 qh[4], ql[4];
    load_q_frags(qhg, qlg, (size_t)bh * NN + tokq, g, qh, ql);
    float rv[16];
    #pragma unroll
    for (int r = 0; r < 16; ++r) {
        const int row = (r & 3) + 8 * (r >> 2) + 4 * g;
        const size_t li = (size_t)bh * NN + idx[b * KPIV + r0 + row];
        rv[r] = 1.0f / (lpart[li] + lpart[NROWS + li]);
    }
    float16 oacc0, oacc1;
    #pragma unroll
    for (int i = 0; i < 16; ++i) { oacc0[i] = 0.f; oacc1[i] = 0.f; }
    const int base_n = th * 2048 + wv * 512;
    for (int step = 0; step < 16; ++step) {
        const int n0 = base_n + step * 32;
        const size_t koff = ((size_t)bh * NN + n0 + ln) * DD + g * 8;
        S_STEP_G(koff)
        __syncthreads();   // pfr(prev step) reads complete everywhere
        #pragma unroll
        for (int r = 0; r < 16; ++r) {
            const int row = (r & 3) + 8 * (r >> 2) + 4 * g;
            const float p = __expf(fmaf(a12[r], C2INV, a0[r])) * rv[r];
            *((ushort_t*)&pfr[wv][ln >> 3][row] + (ln & 7)) = f2bf(p);
        }
        __syncthreads();   // P visible
        #pragma unroll
        for (int kh2 = 0; kh2 < 2; ++kh2) {
            short8 pa = pfr[wv][kh2 * 2 + g][ln];
            const ushort_t* vp0 = vt + ((size_t)bh * DD + ln) * NN + n0 + kh2 * 16 + g * 8;
            uint4 u0 = *(const uint4*)vp0;
            uint4 u1 = *(const uint4*)(vp0 + (size_t)32 * NN);
            short8 vb0, vb1;
            __builtin_memcpy(&vb0, &u0, 16);
            __builtin_memcpy(&vb1, &u1, 16);
            oacc0 = __builtin_amdgcn_mfma_f32_32x32x16_bf16(pa, vb0, oacc0, 0,0,0);
            oacc1 = __builtin_amdgcn_mfma_f32_32x32x16_bf16(pa, vb1, oacc1, 0,0,0);
        }
    }
    #pragma unroll
    for (int r = 0; r < 16; ++r) {
        const int row = (r & 3) + 8 * (r >> 2) + 4 * g;
        osum[wv][row][ln]      = oacc0[r];
        osum[wv][row][32 + ln] = oacc1[r];
    }
    __syncthreads();
    {
        const int qrow = t >> 3, d0 = (t & 7) * 8;
        float s[8] = {};
        #pragma unroll
        for (int w = 0; w < 4; ++w) {
            float4 a  = *(const float4*)&osum[w][qrow][d0];
            float4 b2 = *(const float4*)&osum[w][qrow][d0 + 4];
            s[0] += a.x;  s[1] += a.y;  s[2] += a.z;  s[3] += a.w;
            s[4] += b2.x; s[5] += b2.y; s[6] += b2.z; s[7] += b2.w;
        }
        float* op = opiv + ((size_t)(b * KPIV + r0 + qrow)) * CC + h * DD + d0;
        #pragma unroll
        for (int j = 0; j < 8; ++j) atomicAdd(op + j, s[j]);
    }
}

// ---------------- K7: output projection of pivot rows -> fp32 out -----------
// grid 256 = 128 row-groups x 2 column-halves
__global__ __launch_bounds__(256) void proj_k(
    const float* __restrict__ opiv, const float* __restrict__ wp,
    const float* __restrict__ bp, float* __restrict__ out)
{
    __shared__ __attribute__((aligned(16))) float os[8][CC];
    const int t = threadIdx.x;
    const int r0 = (blockIdx.x >> 1) * 8;
    const int ch = blockIdx.x & 1;
    for (int f = t; f < 1024; f += 256) {
        const int rr = f >> 7, i = (f & 127) * 4;
        *(float4*)&os[rr][i] = *(const float4*)(opiv + (size_t)(r0 + rr) * CC + i);
    }
    __syncthreads();
    const int c0 = ch * 256 + t;
    float acc0[8] = {};
    for (int i = 0; i < CC; ++i) {
        const float w0 = wp[(size_t)i * CC + c0];
        #pragma unroll
        for (int rr = 0; rr < 8; ++rr)
            acc0[rr] = fmaf(os[rr][i], w0, acc0[rr]);
    }
    const float b0 = bp[c0];
    #pragma unroll
    for (int rr = 0; rr < 8; ++rr)
        out[((size_t)(r0 + rr)) * CC + c0] = acc0[rr] + b0;
}

extern "C" void kernel_launch(void* const* d_in, const int* in_sizes, int n_in,
                              void* d_out, int out_size, void* d_ws, size_t ws_size,
                              hipStream_t stream)
{
    const float* x     = (const float*)d_in[0];
    const float* wqkv  = (const float*)d_in[1];
    const float* wproj = (const float*)d_in[2];
    const float* bproj = (const float*)d_in[3];

    // workspace layout: ~50.6 MiB total (all q/k as f16 pairs)
    const size_t NE = (size_t)BB * HH * NN * DD;   // 4.19M elements
    _Float16*  qhg    = (_Float16*)d_ws;                               // 8.39 MB
    _Float16*  qlg    = qhg + NE;                                      // 8.39 MB
    _Float16*  khg    = qlg + NE;                                      // 8.39 MB
    _Float16*  klg    = khg + NE;                                      // 8.39 MB
    ushort_t*  v      = (ushort_t*)(klg + NE);                         // 8.39 MB (d-major)
    float*     lpart  = (float*)(v + NE);                              // 0.52 MB (2 halves)
    float*     colsum = lpart + (size_t)2 * NROWS;                     // 8.39 MB
    double*    imp    = (double*)(colsum + (size_t)512 * NN);          // 0.07 MB
    int*       idx    = (int*)(imp + BB * NN);                         // 4 KB
    float*     opiv   = (float*)(idx + BB * KPIV);                     // 2.10 MB
    float*     out    = (float*)d_out;

    const size_t need = (size_t)((char*)(opiv + (size_t)BB * KPIV * CC) - (char*)d_ws);
    if (ws_size < need) return;   // signature: out stays 0 -> absmax ~0.254

    v_gemm_k<<<dim3(64, 8), 256, 0, stream>>>(x, wqkv, v);
    qkv_gemm_k<<<dim3(64, 8), 256, 0, stream>>>(x, wqkv, qhg, qlg, khg, klg);
    pass_a_k<<<1024, 256, 0, stream>>>(qhg, qlg, khg, klg, lpart);
    pass_b_k<<<1024, 256, 0, stream>>>(qhg, qlg, khg, klg, lpart, colsum);
    imp_reduce_k<<<32, 256, 0, stream>>>(colsum, imp);
    topk_k<<<2, 1024, 0, stream>>>(imp, idx);
    hipMemsetAsync(opiv, 0, (size_t)BB * KPIV * CC * sizeof(float), stream);
    pass_c_k<<<512, 256, 0, stream>>>(qhg, qlg, khg, klg, v, lpart, idx, opiv);
    proj_k<<<256, 256, 0, stream>>>(opiv, wproj, bproj, out);
}

// Round 16
// 628.871 us; speedup vs baseline: 1.0871x; 1.0477x over previous
//
#include <hip/hip_runtime.h>
#include <hip/hip_bf16.h>

#define BB 2
#define NN 4096
#define CC 512
#define HH 8
#define DD 64
#define KPIV 512
#define SCALE 0.125f
#define C2INV 4.8828125e-4f   /* 2^-11 */
#define C2    2048.0f         /* 2^11  */
#define NROWS 65536           /* BB*HH*NN */

typedef unsigned short ushort_t;
typedef __attribute__((ext_vector_type(8))) short short8;
typedef __attribute__((ext_vector_type(8))) _Float16 half8;
typedef __attribute__((ext_vector_type(16))) float float16;

__device__ __forceinline__ float bf2f(ushort_t h) {
    union { unsigned u; float f; } x; x.u = ((unsigned)h) << 16; return x.f;
}
__device__ __forceinline__ ushort_t f2bf(float f) {
    __hip_bfloat16 h = __float2bfloat16(f);
    ushort_t u;
    __builtin_memcpy(&u, &h, sizeof(u));
    return u;
}
// fp32 ~= hi + 2^-11 * lo, both f16, lo prescaled into normal range
__device__ __forceinline__ void split2h(float x, _Float16& hi, _Float16& lo) {
    hi = (_Float16)x;
    lo = (_Float16)((x - (float)hi) * C2);
}

// LDS column packing for the fp32 GEMM: col c -> 8-float groups at 12-float
// pitch. MUST be arithmetic +, not | (round 11 bug: OR aliased columns ->
// LDS write race -> corrupt q/k/v).
#define COLP(c) ((((c) >> 3) * 12) + ((c) & 7))
#define ROWSTR 196   /* floats per kk row */

// ---------------- K1a: Q/K projection GEMM, fp32 VALU (ranking-critical) ----
// NOTE: k and q feeding the importance ranking MUST be computed by this exact
// fp32 accumulation (round 9's MFMA-GEMM k flipped adjacent importance ranks).
// x,w fp32 -> q as (qh,ql) f16 PRESCALED by 0.125, k as (kh,kl) f16
__global__ __launch_bounds__(256) void qkv_gemm_k(
    const float* __restrict__ x, const float* __restrict__ w,
    _Float16* __restrict__ qhg, _Float16* __restrict__ qlg,
    _Float16* __restrict__ khg, _Float16* __restrict__ klg)
{
    __shared__ __attribute__((aligned(16))) float xs[16 * ROWSTR];
    __shared__ __attribute__((aligned(16))) float ws[16 * ROWSTR];
    const int t = threadIdx.x;
    const int row0 = blockIdx.x * 128;
    const int col0 = blockIdx.y * 128;        // 0..1023: ts in {0,1}
    const int tr = t & 15, tc = t >> 4;
    const int ts = col0 >> 9;   // 0=q 1=k, constant per block
    const int xr = t >> 1, xoff = (t & 1) * 8;      // x: row, k-offset
    const int wkk = t >> 4, wc8 = (t & 15) * 8;     // w: k-row, col group
    const float* xpb = x + (size_t)(row0 + xr) * CC + xoff;
    const float* wpb = w + (size_t)wkk * (3 * CC) + col0 + wc8;
    float acc[8][8] = {};
    float4 px0, px1, pw0, pw1;
    px0 = *(const float4*)(xpb);
    px1 = *(const float4*)(xpb + 4);
    pw0 = *(const float4*)(wpb);
    pw1 = *(const float4*)(wpb + 4);
    for (int it = 0; it < 32; ++it) {
        __syncthreads();   // prev iter's LDS reads complete
        {   // write prefetched tile to LDS
            float xv[8] = {px0.x, px0.y, px0.z, px0.w, px1.x, px1.y, px1.z, px1.w};
            const int mc = COLP(xr);
            #pragma unroll
            for (int jj = 0; jj < 8; ++jj)
                xs[(xoff + jj) * ROWSTR + mc] = xv[jj];
            const int nc = wkk * ROWSTR + COLP(wc8);
            *(float4*)&ws[nc]     = pw0;
            *(float4*)&ws[nc + 4] = pw1;
        }
        __syncthreads();   // LDS ready
        if (it + 1 < 32) {  // prefetch next tile; latency hides under compute
            const int k0 = (it + 1) * 16;
            px0 = *(const float4*)(xpb + k0);
            px1 = *(const float4*)(xpb + k0 + 4);
            pw0 = *(const float4*)(wpb + (size_t)k0 * (3 * CC));
            pw1 = *(const float4*)(wpb + (size_t)k0 * (3 * CC) + 4);
        }
        #pragma unroll
        for (int kk = 0; kk < 16; ++kk) {
            float a[8], b[8];
            const int ab = kk * ROWSTR + tr * 12;   // COLP(tr*8) == tr*12
            const int bb = kk * ROWSTR + tc * 12;
            *(float4*)&a[0] = *(const float4*)&xs[ab];
            *(float4*)&a[4] = *(const float4*)&xs[ab + 4];
            *(float4*)&b[0] = *(const float4*)&ws[bb];
            *(float4*)&b[4] = *(const float4*)&ws[bb + 4];
            #pragma unroll
            for (int i = 0; i < 8; ++i)
                #pragma unroll
                for (int j = 0; j < 8; ++j)
                    acc[i][j] = fmaf(a[i], b[j], acc[i][j]);
        }
    }
    const int gc0 = col0 + tc * 8;
    const int hh = (gc0 >> 6) & 7;
    const int dd0 = gc0 & 63;                 // 8-col group within one head
    #pragma unroll
    for (int i = 0; i < 8; ++i) {
        const int grow = row0 + tr * 8 + i;
        const int b = grow >> 12, n = grow & (NN - 1);
        const size_t base = (((size_t)b * HH + hh) * NN + n) * DD + dd0;
        if (ts == 0) {
            half8 h8, l8;
            #pragma unroll
            for (int j = 0; j < 8; ++j) {
                _Float16 a2, b2; split2h(acc[i][j] * SCALE, a2, b2);  // exact *0.125
                h8[j] = a2; l8[j] = b2;
            }
            *(half8*)(qhg + base) = h8;
            *(half8*)(qlg + base) = l8;
        } else {
            half8 h8, l8;
            #pragma unroll
            for (int j = 0; j < 8; ++j) {
                _Float16 a2, b2; split2h(acc[i][j], a2, b2);
                h8[j] = a2; l8[j] = b2;
            }
            *(half8*)(khg + base) = h8;
            *(half8*)(klg + base) = l8;
        }
    }
}

// ---------------- K1b: V projection GEMM via split-f16 MFMA (value path) ----
// v = x @ w[:,1024:1536], output bf16 TRANSPOSED [B,H,D,N]. Value-path only.
__global__ __launch_bounds__(256) void v_gemm_k(
    const float* __restrict__ x, const float* __restrict__ w,
    ushort_t* __restrict__ vt)
{
    __shared__ __attribute__((aligned(16))) _Float16 xh[128 * 24];
    __shared__ __attribute__((aligned(16))) _Float16 xl[128 * 24];
    __shared__ __attribute__((aligned(16))) _Float16 wh[64 * 24];
    __shared__ __attribute__((aligned(16))) _Float16 wl[64 * 24];
    const int t = threadIdx.x;
    const int lane = t & 63, wv = t >> 6;
    const int g = lane >> 5, ln = lane & 31;
    const int row0 = blockIdx.x * 128;
    const int col0 = 1024 + blockIdx.y * 64;
    const int hh = (col0 >> 6) & 7;
    const int b = row0 >> 12;
    float16 a0[2], a12[2];
    #pragma unroll
    for (int c = 0; c < 2; ++c)
        #pragma unroll
        for (int i = 0; i < 16; ++i) { a0[c][i] = 0.f; a12[c][i] = 0.f; }
    for (int k0 = 0; k0 < CC; k0 += 16) {
        __syncthreads();
        {   // stage x tile 128 rows x 16 k, split -> f16 pair, A-frag layout
            const int r = t >> 1, kk0 = (t & 1) * 8;
            const float* xp = x + (size_t)(row0 + r) * CC + k0 + kk0;
            float4 f0 = *(const float4*)xp;
            float4 f1 = *(const float4*)(xp + 4);
            float xv[8] = {f0.x, f0.y, f0.z, f0.w, f1.x, f1.y, f1.z, f1.w};
            half8 h8, l8;
            #pragma unroll
            for (int j = 0; j < 8; ++j) {
                _Float16 a2, b2; split2h(xv[j], a2, b2);
                h8[j] = a2; l8[j] = b2;
            }
            *(half8*)&xh[r * 24 + kk0] = h8;
            *(half8*)&xl[r * 24 + kk0] = l8;
        }
        {   // stage w tile 16 k x 64 cols, split, B-frag layout (col-major)
            const int kk = t & 15, c4 = (t >> 4) * 4;
            float4 f = *(const float4*)(w + (size_t)(k0 + kk) * (3 * CC) + col0 + c4);
            float wv4[4] = {f.x, f.y, f.z, f.w};
            #pragma unroll
            for (int j = 0; j < 4; ++j) {
                _Float16 a2, b2; split2h(wv4[j], a2, b2);
                wh[(c4 + j) * 24 + kk] = a2;
                wl[(c4 + j) * 24 + kk] = b2;
            }
        }
        __syncthreads();
        half8 ah = *(half8*)&xh[(wv * 32 + ln) * 24 + g * 8];
        half8 al = *(half8*)&xl[(wv * 32 + ln) * 24 + g * 8];
        #pragma unroll
        for (int c = 0; c < 2; ++c) {
            half8 bh8 = *(half8*)&wh[(c * 32 + ln) * 24 + g * 8];
            half8 bl8 = *(half8*)&wl[(c * 32 + ln) * 24 + g * 8];
            a0[c]  = __builtin_amdgcn_mfma_f32_32x32x16_f16(ah, bh8, a0[c], 0,0,0);
            a12[c] = __builtin_amdgcn_mfma_f32_32x32x16_f16(al, bh8, a12[c],0,0,0);
            a12[c] = __builtin_amdgcn_mfma_f32_32x32x16_f16(ah, bl8, a12[c],0,0,0);
        }
    }
    // epilogue: transposed v [b,h,d,n]; reg quad rq covers 4 consecutive n
    #pragma unroll
    for (int c = 0; c < 2; ++c) {
        const int d = c * 32 + ln;
        #pragma unroll
        for (int rq = 0; rq < 4; ++rq) {
            const int nbase = row0 + wv * 32 + 8 * rq + 4 * g;
            ushort_t pk[4];
            #pragma unroll
            for (int i = 0; i < 4; ++i) {
                const int r = rq * 4 + i;
                pk[i] = f2bf(fmaf(a12[c][r], C2INV, a0[c][r]));
            }
            __builtin_memcpy(
                vt + ((size_t)(b * HH + hh) * DD + d) * NN + (nbase & (NN - 1)),
                pk, 8);
        }
    }
}

// ---------------- shared S machinery ----------------------------------------
// s = a0(qh.kh) + 2^-11 * a12(ql.kh + qh.kl)
__device__ __forceinline__ void load_q_frags(
    const _Float16* __restrict__ qhg, const _Float16* __restrict__ qlg,
    size_t qrow, int g, half8* qh, half8* ql)
{
    const size_t off = qrow * DD + g * 8;
    #pragma unroll
    for (int kd = 0; kd < 4; ++kd) {
        qh[kd] = *(const half8*)(qhg + off + kd * 16);
        ql[kd] = *(const half8*)(qlg + off + kd * 16);
    }
}

// stage 128 tokens (kh+kl) into LDS: pure copy
__device__ __forceinline__ void stage_k128(
    const _Float16* __restrict__ khg, const _Float16* __restrict__ klg,
    int bh, int n0, int t, half8* khs, half8* kls)
{
    const _Float16* kb = khg + ((size_t)bh * NN + n0) * DD;
    const _Float16* lb = klg + ((size_t)bh * NN + n0) * DD;
    #pragma unroll
    for (int j = 0; j < 4; ++j) {
        const int s = t + j * 256;
        const int seg = s >> 7, tok = s & 127;
        const size_t off = (size_t)tok * DD + seg * 8;
        *(uint4*)&khs[seg * 128 + tok] = *(const uint4*)(kb + off);
        *(uint4*)&kls[seg * 128 + tok] = *(const uint4*)(lb + off);
    }
}

// init + 12 MFMAs into a named accumulator set (explicit pipelining)
#define S_INIT(A0, A12)                                                       \
    _Pragma("unroll")                                                         \
    for (int i = 0; i < 16; ++i) { A0[i] = 0.f; A12[i] = 0.f; }

#define S_MFMA(A0, A12, khsb, klsb, t0)                                       \
    _Pragma("unroll")                                                         \
    for (int kd = 0; kd < 4; ++kd) {                                          \
        half8 bh8 = (khsb)[(kd * 2 + g) * 128 + (t0) + ln];                   \
        half8 bl8 = (klsb)[(kd * 2 + g) * 128 + (t0) + ln];                   \
        A0  = __builtin_amdgcn_mfma_f32_32x32x16_f16(qh[kd], bh8, A0, 0,0,0); \
        A12 = __builtin_amdgcn_mfma_f32_32x32x16_f16(ql[kd], bh8, A12,0,0,0); \
        A12 = __builtin_amdgcn_mfma_f32_32x32x16_f16(qh[kd], bl8, A12,0,0,0); \
    }

#define S_STEP_G(koff)                                                         \
    float16 a0, a12;                                                           \
    _Pragma("unroll")                                                          \
    for (int i = 0; i < 16; ++i) { a0[i] = 0.f; a12[i] = 0.f; }                \
    _Pragma("unroll")                                                          \
    for (int kd = 0; kd < 4; ++kd) {                                           \
        half8 bh8 = *(const half8*)(khg + (koff) + kd * 16);                   \
        half8 bl8 = *(const half8*)(klg + (koff) + kd * 16);                   \
        a0  = __builtin_amdgcn_mfma_f32_32x32x16_f16(qh[kd], bh8, a0, 0,0,0);  \
        a12 = __builtin_amdgcn_mfma_f32_32x32x16_f16(ql[kd], bh8, a12,0,0,0);  \
        a12 = __builtin_amdgcn_mfma_f32_32x32x16_f16(qh[kd], bl8, a12,0,0,0);  \
    }

// ---------------- K2: pass A — l partials, token-half split -----------------
// grid 1024 = (bh x qt) x 2 token-halves. Two accumulator sets pipeline the
// MFMA issue of step i+1 under the exp VALU of step i. exp order per row is
// still step 0,1,2,3 -> rowacc (hence l, ranking) bitwise identical.
__global__ __launch_bounds__(256) void pass_a_k(
    const _Float16* __restrict__ qhg, const _Float16* __restrict__ qlg,
    const _Float16* __restrict__ khg, const _Float16* __restrict__ klg,
    float* __restrict__ lpart)
{
    __shared__ half8 khs[8 * 128];   // 16 KB
    __shared__ half8 kls[8 * 128];   // 16 KB
    const int t = threadIdx.x;
    const int lane = t & 63, wv = t >> 6;
    const int g = lane >> 5, ln = lane & 31;
    const int bh = blockIdx.x >> 6;
    const int qt = (blockIdx.x >> 1) & 31;
    const int th = blockIdx.x & 1;
    const int base_n = th * 2048;
    half8 qh[4], ql[4];
    load_q_frags(qhg, qlg, (size_t)bh * NN + qt * 128 + wv * 32 + ln, g, qh, ql);
    float rowacc[16];
    #pragma unroll
    for (int r = 0; r < 16; ++r) rowacc[r] = 0.f;
    float16 a0A, a12A, a0B, a12B;
    #define A_EXP(A0, A12)                                                    \
        _Pragma("unroll")                                                     \
        for (int r = 0; r < 16; ++r)                                          \
            rowacc[r] += __expf(fmaf(A12[r], C2INV, A0[r]));
    for (int ss = 0; ss < 16; ++ss) {
        __syncthreads();
        stage_k128(khg, klg, bh, base_n + ss * 128, t, khs, kls);
        __syncthreads();
        S_INIT(a0A, a12A) S_MFMA(a0A, a12A, khs, kls, 0)    // step 0 -> A
        S_INIT(a0B, a12B) S_MFMA(a0B, a12B, khs, kls, 32)   // step 1 -> B
        A_EXP(a0A, a12A)                                    // exp step 0
        S_INIT(a0A, a12A) S_MFMA(a0A, a12A, khs, kls, 64)   // step 2 -> A
        A_EXP(a0B, a12B)                                    // exp step 1
        S_INIT(a0B, a12B) S_MFMA(a0B, a12B, khs, kls, 96)   // step 3 -> B
        A_EXP(a0A, a12A)                                    // exp step 2
        A_EXP(a0B, a12B)                                    // exp step 3
    }
    #undef A_EXP
    #pragma unroll
    for (int r = 0; r < 16; ++r) {
        float vs = rowacc[r];
        vs += __shfl_xor(vs, 1);
        vs += __shfl_xor(vs, 2);
        vs += __shfl_xor(vs, 4);
        vs += __shfl_xor(vs, 8);
        vs += __shfl_xor(vs, 16);
        rowacc[r] = vs;
    }
    if (ln == 0) {
        #pragma unroll
        for (int r = 0; r < 16; ++r) {
            const int row = (r & 3) + 8 * (r >> 2) + 4 * g;
            lpart[(size_t)th * NROWS + (size_t)bh * NN + qt * 128 + wv * 32 + row]
                = rowacc[r];
        }
    }
}

// ---------------- K3: pass B — column sums of P -> colsum[512][4096] --------
// Same pipelining; per-step colbuf value computed in identical order ->
// colsum (hence importance) bitwise identical.
__global__ __launch_bounds__(256) void pass_b_k(
    const _Float16* __restrict__ qhg, const _Float16* __restrict__ qlg,
    const _Float16* __restrict__ khg, const _Float16* __restrict__ klg,
    const float* __restrict__ lpart, float* __restrict__ colsum)
{
    __shared__ half8 khs[8 * 128];    // 16 KB
    __shared__ half8 kls[8 * 128];    // 16 KB
    __shared__ float colbuf[4][128];  // 2 KB
    const int t = threadIdx.x;
    const int lane = t & 63, wv = t >> 6;
    const int g = lane >> 5, ln = lane & 31;
    const int bh = blockIdx.x >> 6;
    const int qt = (blockIdx.x >> 1) & 31;
    const int th = blockIdx.x & 1;
    const int rowout = blockIdx.x >> 1;       // bh*32 + qt
    const int base_n = th * 2048;
    half8 qh[4], ql[4];
    load_q_frags(qhg, qlg, (size_t)bh * NN + qt * 128 + wv * 32 + ln, g, qh, ql);
    float rv[16];
    #pragma unroll
    for (int r = 0; r < 16; ++r) {
        const int row = (r & 3) + 8 * (r >> 2) + 4 * g;
        const size_t li = (size_t)bh * NN + qt * 128 + wv * 32 + row;
        rv[r] = 1.0f / (lpart[li] + lpart[NROWS + li]);
    }
    float16 a0A, a12A, a0B, a12B;
    #define B_EXP(A0, A12, ii) {                                              \
        float cs = 0.f;                                                       \
        _Pragma("unroll")                                                     \
        for (int r = 0; r < 16; ++r)                                          \
            cs = fmaf(__expf(fmaf(A12[r], C2INV, A0[r])), rv[r], cs);         \
        cs += __shfl_xor(cs, 32);                                             \
        if (g == 0) colbuf[wv][(ii) * 32 + ln] = cs; }
    for (int ss = 0; ss < 16; ++ss) {
        __syncthreads();   // prev compute reads + colbuf writes complete
        if (ss > 0 && t < 128)   // drain previous superstep's column sums
            colsum[(size_t)rowout * NN + base_n + (ss - 1) * 128 + t] =
                (colbuf[0][t] + colbuf[1][t]) + (colbuf[2][t] + colbuf[3][t]);
        stage_k128(khg, klg, bh, base_n + ss * 128, t, khs, kls);
        __syncthreads();   // staging visible; colbuf consumed
        S_INIT(a0A, a12A) S_MFMA(a0A, a12A, khs, kls, 0)
        S_INIT(a0B, a12B) S_MFMA(a0B, a12B, khs, kls, 32)
        B_EXP(a0A, a12A, 0)
        S_INIT(a0A, a12A) S_MFMA(a0A, a12A, khs, kls, 64)
        B_EXP(a0B, a12B, 1)
        S_INIT(a0B, a12B) S_MFMA(a0B, a12B, khs, kls, 96)
        B_EXP(a0A, a12A, 2)
        B_EXP(a0B, a12B, 3)
    }
    #undef B_EXP
    __syncthreads();
    if (t < 128)
        colsum[(size_t)rowout * NN + base_n + 2048 - 128 + t] =
            (colbuf[0][t] + colbuf[1][t]) + (colbuf[2][t] + colbuf[3][t]);
}

// ---------------- K4: reduce partials -> importance (fp64) ------------------
__global__ __launch_bounds__(256) void imp_reduce_k(
    const float* __restrict__ colsum, double* __restrict__ imp)
{
    const int n = blockIdx.x * 256 + threadIdx.x;   // 0..8191
    const int b = n >> 12, c = n & (NN - 1);
    const float* p = colsum + (size_t)b * 256 * NN + c;
    double s = 0.0;
    for (int i = 0; i < 256; ++i) s += (double)p[(size_t)i * NN];
    imp[n] = s * (1.0 / (double)(HH * NN));
}

// ---------------- K5: exact top-K via full bitonic sort on fp64 keys --------
__global__ __launch_bounds__(1024) void topk_k(
    const double* __restrict__ imp, int* __restrict__ idxout)
{
    __shared__ double sv[4096];
    __shared__ int si[4096];
    const int b = blockIdx.x, t = threadIdx.x;
    for (int i = t; i < 4096; i += 1024) { sv[i] = imp[b * 4096 + i]; si[i] = i; }
    __syncthreads();
    for (int kk = 2; kk <= 4096; kk <<= 1) {
        for (int j = kk >> 1; j > 0; j >>= 1) {
            #pragma unroll 1
            for (int r = 0; r < 2; ++r) {
                const int cm = t + r * 1024;
                const int i = ((cm & ~(j - 1)) << 1) | (cm & (j - 1));
                const int lo = i | j;
                const bool up = ((i & kk) == 0);
                const double va = sv[i], vb = sv[lo];
                const int ia = si[i], ib = si[lo];
                const bool after = (va < vb) || (va == vb && ia > ib);
                if (after == up) { sv[i] = vb; sv[lo] = va; si[i] = ib; si[lo] = ia; }
            }
            __syncthreads();
        }
    }
    if (t < KPIV) idxout[b * KPIV + t] = si[t];
}

// ---------------- K6: O = P@V for pivot rows, MFMA --------------------------
__global__ __launch_bounds__(256) void pass_c_k(
    const _Float16* __restrict__ qhg, const _Float16* __restrict__ qlg,
    const _Float16* __restrict__ khg, const _Float16* __restrict__ klg,
    const ushort_t* __restrict__ vt, const float* __restrict__ lpart,
    const int* __restrict__ idx, float* __restrict__ opiv)
{
    __shared__ short8 pfr[4][4][32];                            // [wv][kh*2+g][q]
    __shared__ __attribute__((aligned(16))) float osum[4][32][64];
    const int t = threadIdx.x;
    const int lane = t & 63, wv = t >> 6;
    const int g = lane >> 5, ln = lane & 31;
    const int bid = blockIdx.x;
    const int b = bid >> 8, h = (bid >> 5) & 7;
    const int chunk = (bid >> 1) & 15, th = bid & 1;
    const int bh = b * HH + h;
    const int r0 = chunk * 32;
    const int tokq = idx[b * KPIV + r0 + ln];
    half8 qh[4], ql[4];
    load_q_frags(qhg, qlg, (size_t)bh * NN + tokq, g, qh, ql);
    float rv[16];
    #pragma unroll
    for (int r = 0; r < 16; ++r) {
        const int row = (r & 3) + 8 * (r >> 2) + 4 * g;
        const size_t li = (size_t)bh * NN + idx[b * KPIV + r0 + row];
        rv[r] = 1.0f / (lpart[li] + lpart[NROWS + li]);
    }
    float16 oacc0, oacc1;
    #pragma unroll
    for (int i = 0; i < 16; ++i) { oacc0[i] = 0.f; oacc1[i] = 0.f; }
    const int base_n = th * 2048 + wv * 512;
    for (int step = 0; step < 16; ++step) {
        const int n0 = base_n + step * 32;
        const size_t koff = ((size_t)bh * NN + n0 + ln) * DD + g * 8;
        S_STEP_G(koff)
        __syncthreads();   // pfr(prev step) reads complete everywhere
        #pragma unroll
        for (int r = 0; r < 16; ++r) {
            const int row = (r & 3) + 8 * (r >> 2) + 4 * g;
            const float p = __expf(fmaf(a12[r], C2INV, a0[r])) * rv[r];
            *((ushort_t*)&pfr[wv][ln >> 3][row] + (ln & 7)) = f2bf(p);
        }
        __syncthreads();   // P visible
        #pragma unroll
        for (int kh2 = 0; kh2 < 2; ++kh2) {
            short8 pa = pfr[wv][kh2 * 2 + g][ln];
            const ushort_t* vp0 = vt + ((size_t)bh * DD + ln) * NN + n0 + kh2 * 16 + g * 8;
            uint4 u0 = *(const uint4*)vp0;
            uint4 u1 = *(const uint4*)(vp0 + (size_t)32 * NN);
            short8 vb0, vb1;
            __builtin_memcpy(&vb0, &u0, 16);
            __builtin_memcpy(&vb1, &u1, 16);
            oacc0 = __builtin_amdgcn_mfma_f32_32x32x16_bf16(pa, vb0, oacc0, 0,0,0);
            oacc1 = __builtin_amdgcn_mfma_f32_32x32x16_bf16(pa, vb1, oacc1, 0,0,0);
        }
    }
    #pragma unroll
    for (int r = 0; r < 16; ++r) {
        const int row = (r & 3) + 8 * (r >> 2) + 4 * g;
        osum[wv][row][ln]      = oacc0[r];
        osum[wv][row][32 + ln] = oacc1[r];
    }
    __syncthreads();
    {
        const int qrow = t >> 3, d0 = (t & 7) * 8;
        float s[8] = {};
        #pragma unroll
        for (int w = 0; w < 4; ++w) {
            float4 a  = *(const float4*)&osum[w][qrow][d0];
            float4 b2 = *(const float4*)&osum[w][qrow][d0 + 4];
            s[0] += a.x;  s[1] += a.y;  s[2] += a.z;  s[3] += a.w;
            s[4] += b2.x; s[5] += b2.y; s[6] += b2.z; s[7] += b2.w;
        }
        float* op = opiv + ((size_t)(b * KPIV + r0 + qrow)) * CC + h * DD + d0;
        #pragma unroll
        for (int j = 0; j < 8; ++j) atomicAdd(op + j, s[j]);
    }
}

// ---------------- K7: output projection of pivot rows -> fp32 out -----------
// grid 256 = 128 row-groups x 2 column-halves
__global__ __launch_bounds__(256) void proj_k(
    const float* __restrict__ opiv, const float* __restrict__ wp,
    const float* __restrict__ bp, float* __restrict__ out)
{
    __shared__ __attribute__((aligned(16))) float os[8][CC];
    const int t = threadIdx.x;
    const int r0 = (blockIdx.x >> 1) * 8;
    const int ch = blockIdx.x & 1;
    for (int f = t; f < 1024; f += 256) {
        const int rr = f >> 7, i = (f & 127) * 4;
        *(float4*)&os[rr][i] = *(const float4*)(opiv + (size_t)(r0 + rr) * CC + i);
    }
    __syncthreads();
    const int c0 = ch * 256 + t;
    float acc0[8] = {};
    for (int i = 0; i < CC; ++i) {
        const float w0 = wp[(size_t)i * CC + c0];
        #pragma unroll
        for (int rr = 0; rr < 8; ++rr)
            acc0[rr] = fmaf(os[rr][i], w0, acc0[rr]);
    }
    const float b0 = bp[c0];
    #pragma unroll
    for (int rr = 0; rr < 8; ++rr)
        out[((size_t)(r0 + rr)) * CC + c0] = acc0[rr] + b0;
}

extern "C" void kernel_launch(void* const* d_in, const int* in_sizes, int n_in,
                              void* d_out, int out_size, void* d_ws, size_t ws_size,
                              hipStream_t stream)
{
    const float* x     = (const float*)d_in[0];
    const float* wqkv  = (const float*)d_in[1];
    const float* wproj = (const float*)d_in[2];
    const float* bproj = (const float*)d_in[3];

    // workspace layout: ~50.6 MiB total (all q/k as f16 pairs)
    const size_t NE = (size_t)BB * HH * NN * DD;   // 4.19M elements
    _Float16*  qhg    = (_Float16*)d_ws;                               // 8.39 MB
    _Float16*  qlg    = qhg + NE;                                      // 8.39 MB
    _Float16*  khg    = qlg + NE;                                      // 8.39 MB
    _Float16*  klg    = khg + NE;                                      // 8.39 MB
    ushort_t*  v      = (ushort_t*)(klg + NE);                         // 8.39 MB (d-major)
    float*     lpart  = (float*)(v + NE);                              // 0.52 MB (2 halves)
    float*     colsum = lpart + (size_t)2 * NROWS;                     // 8.39 MB
    double*    imp    = (double*)(colsum + (size_t)512 * NN);          // 0.07 MB
    int*       idx    = (int*)(imp + BB * NN);                         // 4 KB
    float*     opiv   = (float*)(idx + BB * KPIV);                     // 2.10 MB
    float*     out    = (float*)d_out;

    const size_t need = (size_t)((char*)(opiv + (size_t)BB * KPIV * CC) - (char*)d_ws);
    if (ws_size < need) return;   // signature: out stays 0 -> absmax ~0.254

    v_gemm_k<<<dim3(64, 8), 256, 0, stream>>>(x, wqkv, v);
    qkv_gemm_k<<<dim3(64, 8), 256, 0, stream>>>(x, wqkv, qhg, qlg, khg, klg);
    pass_a_k<<<1024, 256, 0, stream>>>(qhg, qlg, khg, klg, lpart);
    pass_b_k<<<1024, 256, 0, stream>>>(qhg, qlg, khg, klg, lpart, colsum);
    imp_reduce_k<<<32, 256, 0, stream>>>(colsum, imp);
    topk_k<<<2, 1024, 0, stream>>>(imp, idx);
    hipMemsetAsync(opiv, 0, (size_t)BB * KPIV * CC * sizeof(float), stream);
    pass_c_k<<<512, 256, 0, stream>>>(qhg, qlg, khg, klg, v, lpart, idx, opiv);
    proj_k<<<256, 256, 0, stream>>>(opiv, wproj, bproj, out);
}